// Round 4
// baseline (8592.179 us; speedup 1.0000x reference)
//
#include <hip/hip_runtime.h>
#include <hip/hip_bf16.h>
#include <math.h>

#define NB 64
#define NT 512
#define NDIN 256
#define NH 1024
#define NG 4096
#define NDOUT 256

// grid roles: [0,64) z+combine, [64,80) proj, [80,88) out-reduce
#define GRIDN 88
#define LDSB_HIST 147456   // 128K reduce + 16K zfin
#define LDSB_FB   148992   // + 1.5K tables (fallback kernel)

#define HSTEP 131072       // shorts per h time-slab: [v(2)][ku(32)][mb(4)][512]

typedef __attribute__((ext_vector_type(8))) short short8;
typedef __attribute__((ext_vector_type(4))) float float4v;

__device__ __forceinline__ float sigf(float v) { return 1.0f / (1.0f + expf(-v)); }

__device__ __forceinline__ unsigned short bf_hi(float v, float* back) {
    __hip_bfloat16 b = __float2bfloat16(v);
    *back = __bfloat162float(b);
    union { __hip_bfloat16 b; unsigned short u; } cv; cv.b = b;
    return cv.u;
}

// ---- device-coherent (LLC) helpers ----
#define LD8(o0,o1,o2,o3,o4,o5,o6,o7,p0,p1,p2,p3,p4,p5,p6,p7)                     \
  asm volatile("global_load_dwordx4 %0, %8, off sc0 sc1\n\t"                     \
               "global_load_dwordx4 %1, %9, off sc0 sc1\n\t"                     \
               "global_load_dwordx4 %2, %10, off sc0 sc1\n\t"                    \
               "global_load_dwordx4 %3, %11, off sc0 sc1\n\t"                    \
               "global_load_dwordx4 %4, %12, off sc0 sc1\n\t"                    \
               "global_load_dwordx4 %5, %13, off sc0 sc1\n\t"                    \
               "global_load_dwordx4 %6, %14, off sc0 sc1\n\t"                    \
               "global_load_dwordx4 %7, %15, off sc0 sc1\n\t"                    \
               "s_waitcnt vmcnt(0)"                                              \
               : "=&v"(o0),"=&v"(o1),"=&v"(o2),"=&v"(o3),                        \
                 "=&v"(o4),"=&v"(o5),"=&v"(o6),"=&v"(o7)                         \
               : "v"(p0),"v"(p1),"v"(p2),"v"(p3),"v"(p4),"v"(p5),"v"(p6),"v"(p7) \
               : "memory")

#define LD2(o0,o1,p0,p1)                                                         \
  asm volatile("global_load_dwordx4 %0, %2, off sc0 sc1\n\t"                     \
               "global_load_dwordx4 %1, %3, off sc0 sc1\n\t"                     \
               "s_waitcnt vmcnt(0)"                                              \
               : "=&v"(o0),"=&v"(o1) : "v"(p0),"v"(p1) : "memory")

__device__ __forceinline__ void sc_store_short(unsigned short* p, unsigned short v) {
    asm volatile("global_store_short %0, %1, off sc0 sc1" :: "v"(p), "v"((unsigned)v) : "memory");
}
__device__ __forceinline__ void sc_store_dword(float* p, float v) {
    asm volatile("global_store_dword %0, %1, off sc0 sc1" :: "v"(p), "v"(v) : "memory");
}

// Monotonic-counter grid barrier. All cross-block data is either sc0/sc1
// (write-through, LLC) or written to fresh addresses each step (h history),
// so no cache maintenance is needed: drain own stores + one LLC atomic.
__device__ __forceinline__ void gbar(unsigned* cnt, unsigned tgt) {
    asm volatile("s_waitcnt vmcnt(0)" ::: "memory");
    __syncthreads();
    if (threadIdx.x == 0) {
        __hip_atomic_fetch_add(cnt, 1u, __ATOMIC_RELAXED, __HIP_MEMORY_SCOPE_AGENT);
        while (__hip_atomic_load(cnt, __ATOMIC_RELAXED, __HIP_MEMORY_SCOPE_AGENT) < tgt) {}
    }
    __syncthreads();
}

__global__ void zero_kernel(float* __restrict__ p, int n) {
    int i = blockIdx.x * 256 + threadIdx.x;
    if (i < n) p[i] = 0.0f;
}

// W (= [Wx;Wh], 1280 x 4096) -> B-frag order [nb(256)][ku(40)][lane(64)][j(8)], hi/lo
__global__ void packW_kernel(const float* __restrict__ Wx, const float* __restrict__ Wh,
                             unsigned short* __restrict__ W0f, unsigned short* __restrict__ W1f) {
    int e = blockIdx.x * 256 + threadIdx.x;
    if (e >= 1280 * 4096) return;
    int k = e >> 12, n = e & 4095;
    float w = (k < NDIN) ? Wx[(size_t)k * NG + n] : Wh[(size_t)(k - NDIN) * NG + n];
    float back;
    unsigned short w0 = bf_hi(w, &back);
    unsigned short w1 = bf_hi(w - back, &back);
    int nb = n >> 4, nl = n & 15, ku = k >> 5, kr = k & 31;
    int lane = (kr >> 3) * 16 + nl, j = kr & 7;
    size_t off = (((size_t)nb * 40 + ku) * 64 + lane) * 8 + j;
    W0f[off] = w0; W1f[off] = w1;
}

// x ([64][512][256]) -> A-frag order [t][ku(8)][mb(4)][lane(64)][j(8)], hi/lo
__global__ void packX_kernel(const float* __restrict__ x,
                             unsigned short* __restrict__ xf0, unsigned short* __restrict__ xf1) {
    int e = blockIdx.x * 256 + threadIdx.x;
    if (e >= NB * NT * NDIN) return;
    int k = e & 255, t = (e >> 8) & 511, m = e >> 17;
    float v = x[e];
    float back;
    unsigned short a0 = bf_hi(v, &back);
    unsigned short a1 = bf_hi(v - back, &back);
    int ku = k >> 5, kr = k & 31, mb = m >> 4;
    int lane = (kr >> 3) * 16 + (m & 15), j = kr & 7;
    size_t off = ((((size_t)t * 8 + ku) * 4 + mb) * 64 + lane) * 8 + j;
    xf0[off] = a0; xf1[off] = a1;
}

// Wo (1024 x 256) -> B-frag order [nb(16)][ku(32)][lane(64)][j(8)], hi/lo
__global__ void packWo_kernel(const float* __restrict__ Wo,
                              unsigned short* __restrict__ Wo0f, unsigned short* __restrict__ Wo1f) {
    int e = blockIdx.x * 256 + threadIdx.x;
    if (e >= NH * NDOUT) return;
    int k = e >> 8, n = e & 255;
    float w = Wo[e];
    float back;
    unsigned short w0 = bf_hi(w, &back);
    unsigned short w1 = bf_hi(w - back, &back);
    int nb = n >> 4, nl = n & 15, ku = k >> 5, kr = k & 31;
    int lane = (kr >> 3) * 16 + nl, j = kr & 7;
    size_t off = (((size_t)nb * 32 + ku) * 64 + lane) * 8 + j;
    Wo0f[off] = w0; Wo1f[off] = w1;
}

// ===================== history-buffer persistent kernel ======================
// W is loop-invariant: z-waves preload 3 of their 5 ku W-frag sets (both hi/lo
// planes, all 4 gates = 24 short8 = 96 VGPR) into registers before the t-loop;
// only 2 ku stream from L2 each step. Proj waves are re-tiled (K-half x mb) so
// each wave's unique Wo slice is exactly 32 frags = 128 VGPR -> fully
// register-resident; proj A-reads drop to the unique 256 KB (K-half partials
// land in op rows 0-63/64-127 exactly like the old pksl split, summed by
// outred). h state gets a FRESH 256KB slab per step (cached reads safe).
__global__ __launch_bounds__(512, 2) void persist_hist_kernel(
    const unsigned short* __restrict__ W0f, const unsigned short* __restrict__ W1f,
    const unsigned short* __restrict__ xf0, const unsigned short* __restrict__ xf1,
    const unsigned short* __restrict__ Wo0f, const unsigned short* __restrict__ Wo1f,
    unsigned short* __restrict__ hh, float* __restrict__ cst,
    float* __restrict__ opart, const float* __restrict__ bias,
    const float* __restrict__ bo, float* __restrict__ out, unsigned* __restrict__ bar)
{
    extern __shared__ char dynlds[];
    float* red  = (float*)dynlds;                    // [8][4096]
    float* zfin = (float*)(dynlds + 131072);         // [4096]

    const int bid = blockIdx.x, tid = threadIdx.x;
    const int lane = tid & 63, w = tid >> 6;

    // ---- loop-invariant register preloads ----
    short8 Wr0[3][4], Wr1[3][4];                     // z: ku0..ku0+2, 4 gates, hi/lo
    short8 Po0[16], Po1[16];                         // proj: K-half Wo slice, hi/lo
    if (bid < 64) {
        const int jt = bid, ku0 = w * 5;
        #pragma unroll
        for (int i = 0; i < 3; ++i)
            #pragma unroll
            for (int g = 0; g < 4; ++g) {
                size_t off = (((size_t)(g * 64 + jt) * 40 + (ku0 + i)) * 64 + lane) * 8;
                Wr0[i][g] = *(const short8*)(W0f + off);
                Wr1[i][g] = *(const short8*)(W1f + off);
            }
    } else if (bid < 80) {
        const int pnb = bid - 64;
        const int kh = w >> 2;                       // 0..1 K-half
        const unsigned short* wb0 = Wo0f + (size_t)pnb * 32 * 512;
        const unsigned short* wb1 = Wo1f + (size_t)pnb * 32 * 512;
        #pragma unroll
        for (int kk = 0; kk < 16; ++kk) {
            Po0[kk] = *(const short8*)(wb0 + (size_t)(kh * 16 + kk) * 512 + lane * 8);
            Po1[kk] = *(const short8*)(wb1 + (size_t)(kh * 16 + kk) * 512 + lane * 8);
        }
    }

    for (int t = 0; t <= NT + 1; ++t) {
        if (bid < 64) {
            if (t < NT) {
                // ---- z + block-local combine: 16 h-cols (jt), all 4 gates ----
                const int jt = bid;
                float4v acc[4][4];                            // [mb][gate]
                #pragma unroll
                for (int mb = 0; mb < 4; ++mb)
                    #pragma unroll
                    for (int g = 0; g < 4; ++g)
                        acc[mb][g] = (float4v){0.f, 0.f, 0.f, 0.f};

                const unsigned short* hbase = hh + (size_t)t * HSTEP;
                const int ku0 = w * 5;                        // wave-private K slice
                #pragma unroll
                for (int i = 0; i < 5; ++i) {
                    const int ku = ku0 + i;
                    short8 A0[4], A1[4], Wh[4], Wl[4];
                    const unsigned short *p0, *p1;
                    if (ku < 8) {
                        p0 = xf0 + ((size_t)t * 8 + ku) * 2048;
                        p1 = xf1 + ((size_t)t * 8 + ku) * 2048;
                    } else {
                        p0 = hbase + (size_t)(ku - 8) * 2048;
                        p1 = hbase + 65536 + (size_t)(ku - 8) * 2048;
                    }
                    #pragma unroll
                    for (int mb = 0; mb < 4; ++mb) {
                        A0[mb] = *(const short8*)(p0 + mb * 512 + lane * 8);
                        A1[mb] = *(const short8*)(p1 + mb * 512 + lane * 8);
                    }
                    if (i < 3) {
                        #pragma unroll
                        for (int g = 0; g < 4; ++g) { Wh[g] = Wr0[i][g]; Wl[g] = Wr1[i][g]; }
                    } else {
                        #pragma unroll
                        for (int g = 0; g < 4; ++g) {
                            size_t off = (((size_t)(g * 64 + jt) * 40 + ku) * 64 + lane) * 8;
                            Wh[g] = *(const short8*)(W0f + off);
                            Wl[g] = *(const short8*)(W1f + off);
                        }
                    }
                    #pragma unroll
                    for (int mb = 0; mb < 4; ++mb)
                        #pragma unroll
                        for (int g = 0; g < 4; ++g) {
                            acc[mb][g] = __builtin_amdgcn_mfma_f32_16x16x32_bf16(A0[mb], Wh[g], acc[mb][g], 0, 0, 0);
                            acc[mb][g] = __builtin_amdgcn_mfma_f32_16x16x32_bf16(A0[mb], Wl[g], acc[mb][g], 0, 0, 0);
                            acc[mb][g] = __builtin_amdgcn_mfma_f32_16x16x32_bf16(A1[mb], Wh[g], acc[mb][g], 0, 0, 0);
                        }
                }

                // cross-wave splitK reduce via LDS
                {
                    float* slab = red + w * 4096;
                    #pragma unroll
                    for (int mb = 0; mb < 4; ++mb)
                        #pragma unroll
                        for (int g = 0; g < 4; ++g)
                            *(float4v*)&slab[((mb * 4 + g) * 64 + lane) * 4] = acc[mb][g];
                }
                __syncthreads();
                for (int s = tid; s < 1024; s += 512) {
                    float4v sum = (float4v){0.f, 0.f, 0.f, 0.f};
                    #pragma unroll
                    for (int ww = 0; ww < 8; ++ww)
                        sum = sum + *(const float4v*)&red[ww * 4096 + s * 4];
                    *(float4v*)&zfin[s * 4] = sum;
                }
                __syncthreads();

                // gate math + cell update + h write to FRESH slab t+1 (sc write-through)
                unsigned short* hw = hh + (size_t)(t + 1) * HSTEP;
                for (int e = tid; e < 1024; e += 512) {
                    const int row = e >> 4, col = e & 15;
                    const int j = jt * 16 + col;
                    const int mb = row >> 4, q4 = (row >> 2) & 3, r = row & 3;
                    const int ln = q4 * 16 + col;
                    float zi = zfin[((mb * 4 + 0) * 64 + ln) * 4 + r] + bias[j];
                    float zf = zfin[((mb * 4 + 1) * 64 + ln) * 4 + r] + bias[NH + j];
                    float zg = zfin[((mb * 4 + 2) * 64 + ln) * 4 + r] + bias[2 * NH + j];
                    float zo = zfin[((mb * 4 + 3) * 64 + ln) * 4 + r] + bias[3 * NH + j];
                    float iv = sigf(zi), fv = sigf(zf), gv = tanhf(zg), ov = sigf(zo);
                    const size_t ci = (size_t)row * NH + j;   // block-exclusive: normal cached
                    float cv = fv * cst[ci] + iv * gv;
                    cst[ci] = cv;
                    float hv = ov * tanhf(cv);
                    float back;
                    unsigned short h0 = bf_hi(hv, &back);
                    unsigned short h1 = bf_hi(hv - back, &back);
                    const int ku = j >> 5, kr = j & 31;
                    const int lane2 = (kr >> 3) * 16 + (row & 15), jj = kr & 7;
                    size_t base = ((size_t)ku * 4 + mb) * 512 + lane2 * 8 + jj;
                    sc_store_short(hw + base, h0);
                    sc_store_short(hw + base + 65536, h1);    // v=1 plane
                }
            }
        } else if (bid < 80) {
            // ---- projection of h slab t (= h of step t-1) -> opart[t&1] ----
            // wave (kh = K-half, mbw = batch 16-row group); Wo fully in regs.
            if (t >= 1 && t <= NT) {
                const int pnb = bid - 64;
                const int kh = w >> 2, mbw = w & 3;
                const unsigned short* hb = hh + (size_t)t * HSTEP
                                         + (size_t)(kh * 16) * 2048 + mbw * 512 + lane * 8;
                float4v pacc = (float4v){0.f, 0.f, 0.f, 0.f};
                #pragma unroll
                for (int kk = 0; kk < 16; ++kk) {
                    short8 Ahi = *(const short8*)(hb + (size_t)kk * 2048);
                    short8 Alo = *(const short8*)(hb + 65536 + (size_t)kk * 2048);
                    pacc = __builtin_amdgcn_mfma_f32_16x16x32_bf16(Ahi, Po0[kk], pacc, 0, 0, 0);
                    pacc = __builtin_amdgcn_mfma_f32_16x16x32_bf16(Ahi, Po1[kk], pacc, 0, 0, 0);
                    pacc = __builtin_amdgcn_mfma_f32_16x16x32_bf16(Alo, Po0[kk], pacc, 0, 0, 0);
                }
                const int q4 = lane >> 4, nl16 = lane & 15;
                float* op = opart + (size_t)(t & 1) * 32768;
                #pragma unroll
                for (int r = 0; r < 4; ++r)
                    sc_store_dword(op + ((size_t)(kh * 64 + mbw * 16 + q4 * 4 + r)) * NDOUT + pnb * 16 + nl16,
                                   pacc[r]);
            }
        } else {
            // ---- out-reduce of opart[(t-1)&1] -> row t-2 ----
            if (t >= 2) {
                const int ob = bid - 80;
                const float* op = opart + (size_t)((t - 1) & 1) * 32768;
                int idx = ob * 512 + tid;                     // [0,4096)
                int m = idx >> 6, oc4 = (idx & 63) * 4;
                float4v s0, s1;
                LD2(s0, s1, &op[(size_t)m * NDOUT + oc4], &op[(size_t)(64 + m) * NDOUT + oc4]);
                float4v bv = *(const float4v*)&bo[oc4];
                float4v v = s0 + s1 + bv;
                float4v rr;
                rr[0] = fmaxf(v[0], 0.f); rr[1] = fmaxf(v[1], 0.f);
                rr[2] = fmaxf(v[2], 0.f); rr[3] = fmaxf(v[3], 0.f);
                *(float4v*)&out[((size_t)m * NT + (t - 2)) * NDOUT + oc4] = rr;
            }
        }

        gbar(bar, (unsigned)(t + 1) * GRIDN);
    }
}

// ===================== fallback (round-2) kernel: used only if ws too small ==
__global__ __launch_bounds__(512, 2) void persist_kernel(
    const unsigned short* __restrict__ W0f, const unsigned short* __restrict__ W1f,
    const unsigned short* __restrict__ xf0, const unsigned short* __restrict__ xf1,
    const unsigned short* __restrict__ Wo0f, const unsigned short* __restrict__ Wo1f,
    unsigned short* __restrict__ hf, float* __restrict__ cst,
    float* __restrict__ opart, const float* __restrict__ bias,
    const float* __restrict__ bo, float* __restrict__ out, unsigned* __restrict__ bar)
{
    extern __shared__ char dynlds[];
    float* red  = (float*)dynlds;
    float* zfin = (float*)(dynlds + 131072);
    const unsigned short** tabA = (const unsigned short**)(dynlds + 147456);
    const unsigned short** tabW = tabA + 96;

    const int bid = blockIdx.x, tid = threadIdx.x;
    const int lane = tid & 63, w = tid >> 6;

    if (bid >= 64 && bid < 80) {
        const int pnb = bid - 64;
        for (int i = tid; i < 96; i += 512) {
            int q = i / 32, ku = i % 32, v = (q == 2);
            tabA[i] = hf + (((size_t)(v * 2) * 32 + ku) * 4) * 512;
            tabW[i] = ((q == 1) ? Wo1f : Wo0f) + (size_t)pnb * 32 * 512 + (size_t)ku * 512;
        }
        __syncthreads();
    }

    for (int t = 0; t <= NT + 1; ++t) {
        const int buf = t & 1, nbuf = (t + 1) & 1;
        if (bid < 64) {
            if (t < NT) {
                const int jt = bid;
                float4v acc[4][4];
                #pragma unroll
                for (int mb = 0; mb < 4; ++mb)
                    #pragma unroll
                    for (int g = 0; g < 4; ++g)
                        acc[mb][g] = (float4v){0.f, 0.f, 0.f, 0.f};
                const int ku0 = w * 5;
                #pragma unroll
                for (int i = 0; i < 5; ++i) {
                    const int ku = ku0 + i;
                    short8 A0[4], A1[4], Wh[4], Wl[4];
                    if (ku < 8) {
                        const unsigned short* x0 = xf0 + ((size_t)t * 8 + ku) * 2048;
                        const unsigned short* x1 = xf1 + ((size_t)t * 8 + ku) * 2048;
                        #pragma unroll
                        for (int mb = 0; mb < 4; ++mb) {
                            A0[mb] = *(const short8*)(x0 + mb * 512 + lane * 8);
                            A1[mb] = *(const short8*)(x1 + mb * 512 + lane * 8);
                        }
                    } else {
                        const unsigned short* h0b = hf + ((size_t)buf * 32 + (ku - 8)) * 2048 + lane * 8;
                        const unsigned short* h1b = hf + ((size_t)(2 + buf) * 32 + (ku - 8)) * 2048 + lane * 8;
                        LD8(A0[0], A0[1], A0[2], A0[3], A1[0], A1[1], A1[2], A1[3],
                            h0b, h0b + 512, h0b + 1024, h0b + 1536,
                            h1b, h1b + 512, h1b + 1024, h1b + 1536);
                    }
                    #pragma unroll
                    for (int g = 0; g < 4; ++g) {
                        size_t off = (((size_t)(g * 64 + jt) * 40 + ku) * 64 + lane) * 8;
                        Wh[g] = *(const short8*)(W0f + off);
                        Wl[g] = *(const short8*)(W1f + off);
                    }
                    #pragma unroll
                    for (int mb = 0; mb < 4; ++mb)
                        #pragma unroll
                        for (int g = 0; g < 4; ++g) {
                            acc[mb][g] = __builtin_amdgcn_mfma_f32_16x16x32_bf16(A0[mb], Wh[g], acc[mb][g], 0, 0, 0);
                            acc[mb][g] = __builtin_amdgcn_mfma_f32_16x16x32_bf16(A0[mb], Wl[g], acc[mb][g], 0, 0, 0);
                            acc[mb][g] = __builtin_amdgcn_mfma_f32_16x16x32_bf16(A1[mb], Wh[g], acc[mb][g], 0, 0, 0);
                        }
                }
                {
                    float* slab = red + w * 4096;
                    #pragma unroll
                    for (int mb = 0; mb < 4; ++mb)
                        #pragma unroll
                        for (int g = 0; g < 4; ++g)
                            *(float4v*)&slab[((mb * 4 + g) * 64 + lane) * 4] = acc[mb][g];
                }
                __syncthreads();
                for (int s = tid; s < 1024; s += 512) {
                    float4v sum = (float4v){0.f, 0.f, 0.f, 0.f};
                    #pragma unroll
                    for (int ww = 0; ww < 8; ++ww)
                        sum = sum + *(const float4v*)&red[ww * 4096 + s * 4];
                    *(float4v*)&zfin[s * 4] = sum;
                }
                __syncthreads();
                for (int e = tid; e < 1024; e += 512) {
                    const int row = e >> 4, col = e & 15;
                    const int j = jt * 16 + col;
                    const int mb = row >> 4, q4 = (row >> 2) & 3, r = row & 3;
                    const int ln = q4 * 16 + col;
                    float zi = zfin[((mb * 4 + 0) * 64 + ln) * 4 + r] + bias[j];
                    float zf = zfin[((mb * 4 + 1) * 64 + ln) * 4 + r] + bias[NH + j];
                    float zg = zfin[((mb * 4 + 2) * 64 + ln) * 4 + r] + bias[2 * NH + j];
                    float zo = zfin[((mb * 4 + 3) * 64 + ln) * 4 + r] + bias[3 * NH + j];
                    float iv = sigf(zi), fv = sigf(zf), gv = tanhf(zg), ov = sigf(zo);
                    const size_t ci = (size_t)row * NH + j;
                    float cv = fv * cst[ci] + iv * gv;
                    cst[ci] = cv;
                    float hv = ov * tanhf(cv);
                    float back;
                    unsigned short h0 = bf_hi(hv, &back);
                    unsigned short h1 = bf_hi(hv - back, &back);
                    const int ku = j >> 5, kr = j & 31;
                    const int lane2 = (kr >> 3) * 16 + (row & 15), jj = kr & 7;
                    size_t base = (((size_t)nbuf * 32 + ku) * 4 + mb) * 512 + lane2 * 8 + jj;
                    sc_store_short(hf + base, h0);
                    sc_store_short(hf + base + 131072, h1);
                }
            }
        } else if (bid < 80) {
            if (t >= 1 && t <= NT) {
                const size_t bufofs = (size_t)buf * 65536;
                const int pksl = w >> 2, mbw = w & 3;
                float4v pacc = (float4v){0.f, 0.f, 0.f, 0.f};
                #pragma unroll
                for (int bb = 0; bb < 6; ++bb) {
                    const int ibase = pksl * 48 + bb * 8;
                    short8 A[8];
                    const unsigned short* ap[8];
                    #pragma unroll
                    for (int u = 0; u < 8; ++u)
                        ap[u] = tabA[ibase + u] + bufofs + mbw * 512 + lane * 8;
                    LD8(A[0], A[1], A[2], A[3], A[4], A[5], A[6], A[7],
                        ap[0], ap[1], ap[2], ap[3], ap[4], ap[5], ap[6], ap[7]);
                    #pragma unroll
                    for (int u = 0; u < 8; ++u) {
                        short8 Bv = *(const short8*)(tabW[ibase + u] + lane * 8);
                        pacc = __builtin_amdgcn_mfma_f32_16x16x32_bf16(A[u], Bv, pacc, 0, 0, 0);
                    }
                }
                const int pnb = bid - 64;
                const int q4 = lane >> 4, nl16 = lane & 15;
                float* op = opart + (size_t)(t & 1) * 32768;
                #pragma unroll
                for (int r = 0; r < 4; ++r)
                    sc_store_dword(op + ((size_t)(pksl * 64 + mbw * 16 + q4 * 4 + r)) * NDOUT + pnb * 16 + nl16,
                                   pacc[r]);
            }
        } else {
            if (t >= 2) {
                const int ob = bid - 80;
                const float* op = opart + (size_t)((t - 1) & 1) * 32768;
                int idx = ob * 512 + tid;
                int m = idx >> 6, oc4 = (idx & 63) * 4;
                float4v s0, s1;
                LD2(s0, s1, &op[(size_t)m * NDOUT + oc4], &op[(size_t)(64 + m) * NDOUT + oc4]);
                float4v bv = *(const float4v*)&bo[oc4];
                float4v v = s0 + s1 + bv;
                float4v rr;
                rr[0] = fmaxf(v[0], 0.f); rr[1] = fmaxf(v[1], 0.f);
                rr[2] = fmaxf(v[2], 0.f); rr[3] = fmaxf(v[3], 0.f);
                *(float4v*)&out[((size_t)m * NT + (t - 2)) * NDOUT + oc4] = rr;
            }
        }
        gbar(bar, (unsigned)(t + 1) * GRIDN);
    }
}

extern "C" void kernel_launch(void* const* d_in, const int* in_sizes, int n_in,
                              void* d_out, int out_size, void* d_ws, size_t ws_size,
                              hipStream_t stream) {
    const float* x  = (const float*)d_in[0];
    const float* Wx = (const float*)d_in[1];
    const float* Wh = (const float*)d_in[2];
    const float* b  = (const float*)d_in[3];
    const float* Wo = (const float*)d_in[4];
    const float* bo = (const float*)d_in[5];
    float* out = (float*)d_out;
    char* ws = (char*)d_ws;

    // history layout sizing
    const size_t hh_bytes = (size_t)(NT + 1) * HSTEP * 2;     // 513 x 256 KB = 134.5 MB
    size_t need = 0;
    need += (size_t)NB * NH * 4;          // cst
    need += 256;                          // bar
    need += hh_bytes;                     // hh
    need += (size_t)2 * 2 * NB * NDOUT * 4;
    need += (size_t)1280 * 4096 * 2 * 2;  // W0f/W1f
    need += (size_t)NH * NDOUT * 2 * 2;   // Wo0f/Wo1f
    need += (size_t)NB * NT * NDIN * 2 * 2; // xf0/xf1

    if (ws_size >= need) {
        size_t off = 0;
        float* cst    = (float*)(ws + off);               off += (size_t)NB * NH * 4;   // 256 KB
        unsigned* bar = (unsigned*)(ws + off);            off += 256;
        unsigned short* hh = (unsigned short*)(ws + off); off += hh_bytes;
        size_t zero_floats = ((size_t)NB * NH * 4 + 256 + (size_t)HSTEP * 2) / 4; // cst+bar+hh[0]
        float* opart = (float*)(ws + off);                off += (size_t)2 * 2 * NB * NDOUT * 4;
        unsigned short* W0f = (unsigned short*)(ws + off); off += (size_t)1280 * 4096 * 2;
        unsigned short* W1f = (unsigned short*)(ws + off); off += (size_t)1280 * 4096 * 2;
        unsigned short* Wo0f = (unsigned short*)(ws + off); off += (size_t)NH * NDOUT * 2;
        unsigned short* Wo1f = (unsigned short*)(ws + off); off += (size_t)NH * NDOUT * 2;
        unsigned short* xf0 = (unsigned short*)(ws + off); off += (size_t)NB * NT * NDIN * 2;
        unsigned short* xf1 = (unsigned short*)(ws + off); off += (size_t)NB * NT * NDIN * 2;

        zero_kernel<<<(int)((zero_floats + 255) / 256), 256, 0, stream>>>((float*)ws, (int)zero_floats);
        packW_kernel<<<(1280 * 4096 + 255) / 256, 256, 0, stream>>>(Wx, Wh, W0f, W1f);
        packX_kernel<<<(NB * NT * NDIN + 255) / 256, 256, 0, stream>>>(x, xf0, xf1);
        packWo_kernel<<<(NH * NDOUT + 255) / 256, 256, 0, stream>>>(Wo, Wo0f, Wo1f);

        void* args[] = {(void*)&W0f, (void*)&W1f, (void*)&xf0, (void*)&xf1,
                        (void*)&Wo0f, (void*)&Wo1f, (void*)&hh, (void*)&cst,
                        (void*)&opart, (void*)&b, (void*)&bo, (void*)&out, (void*)&bar};
        hipLaunchCooperativeKernel((void*)persist_hist_kernel, dim3(GRIDN), dim3(512),
                                   args, (unsigned)LDSB_HIST, stream);
    } else {
        size_t off = 0;
        float* cst    = (float*)(ws + off);               off += (size_t)NB * NH * 4;
        unsigned short* hf = (unsigned short*)(ws + off); off += (size_t)2 * 2 * 32 * 4 * 512 * 2;
        unsigned* bar = (unsigned*)(ws + off);            off += 256;
        size_t zero_floats = off / 4;
        float* opart = (float*)(ws + off);                off += (size_t)2 * 2 * NB * NDOUT * 4;
        unsigned short* W0f = (unsigned short*)(ws + off); off += (size_t)1280 * 4096 * 2;
        unsigned short* W1f = (unsigned short*)(ws + off); off += (size_t)1280 * 4096 * 2;
        unsigned short* Wo0f = (unsigned short*)(ws + off); off += (size_t)NH * NDOUT * 2;
        unsigned short* Wo1f = (unsigned short*)(ws + off); off += (size_t)NH * NDOUT * 2;
        unsigned short* xf0 = (unsigned short*)(ws + off); off += (size_t)NB * NT * NDIN * 2;
        unsigned short* xf1 = (unsigned short*)(ws + off); off += (size_t)NB * NT * NDIN * 2;

        zero_kernel<<<(int)((zero_floats + 255) / 256), 256, 0, stream>>>((float*)ws, (int)zero_floats);
        packW_kernel<<<(1280 * 4096 + 255) / 256, 256, 0, stream>>>(Wx, Wh, W0f, W1f);
        packX_kernel<<<(NB * NT * NDIN + 255) / 256, 256, 0, stream>>>(x, xf0, xf1);
        packWo_kernel<<<(NH * NDOUT + 255) / 256, 256, 0, stream>>>(Wo, Wo0f, Wo1f);

        void* args[] = {(void*)&W0f, (void*)&W1f, (void*)&xf0, (void*)&xf1,
                        (void*)&Wo0f, (void*)&Wo1f, (void*)&hf, (void*)&cst,
                        (void*)&opart, (void*)&b, (void*)&bo, (void*)&out, (void*)&bar};
        hipLaunchCooperativeKernel((void*)persist_kernel, dim3(GRIDN), dim3(512),
                                   args, (unsigned)LDSB_FB, stream);
    }
}

// Round 5
// 7430.665 us; speedup vs baseline: 1.1563x; 1.1563x over previous
//
#include <hip/hip_runtime.h>
#include <hip/hip_bf16.h>
#include <math.h>

#define NB 64
#define NT 512
#define NDIN 256
#define NH 1024
#define NG 4096
#define NDOUT 256

// 256 blocks: ALL do z (4 h-cols each); [0,128) also proj; [128,136) also outred
#define GRIDN 256
#define LDSB 118784        // 80K Wz + 32K red + 4K zfin
#define HSTEP 131072       // shorts per h time-slab: [v(2)][ku(32)][mb(4)][512]

typedef __attribute__((ext_vector_type(8))) short short8;
typedef __attribute__((ext_vector_type(4))) float float4v;

__device__ __forceinline__ float sigf(float v) { return 1.0f / (1.0f + expf(-v)); }

__device__ __forceinline__ unsigned short bf_hi(float v, float* back) {
    __hip_bfloat16 b = __float2bfloat16(v);
    *back = __bfloat162float(b);
    union { __hip_bfloat16 b; unsigned short u; } cv; cv.b = b;
    return cv.u;
}

// ---- device-coherent (LLC) helpers ----
#define LD2(o0,o1,p0,p1)                                                         \
  asm volatile("global_load_dwordx4 %0, %2, off sc0 sc1\n\t"                     \
               "global_load_dwordx4 %1, %3, off sc0 sc1\n\t"                     \
               "s_waitcnt vmcnt(0)"                                              \
               : "=&v"(o0),"=&v"(o1) : "v"(p0),"v"(p1) : "memory")

__device__ __forceinline__ void sc_store_short(unsigned short* p, unsigned short v) {
    asm volatile("global_store_short %0, %1, off sc0 sc1" :: "v"(p), "v"((unsigned)v) : "memory");
}
__device__ __forceinline__ void sc_store_dword(float* p, float v) {
    asm volatile("global_store_dword %0, %1, off sc0 sc1" :: "v"(p), "v"(v) : "memory");
}

// Monotonic-counter grid barrier (validated r2-r4). Cross-block data is sc0/sc1
// write-through or fresh-address cached reads -> no cache maintenance needed.
__device__ __forceinline__ void gbar(unsigned* cnt, unsigned tgt) {
    asm volatile("s_waitcnt vmcnt(0)" ::: "memory");
    __syncthreads();
    if (threadIdx.x == 0) {
        __hip_atomic_fetch_add(cnt, 1u, __ATOMIC_RELAXED, __HIP_MEMORY_SCOPE_AGENT);
        while (__hip_atomic_load(cnt, __ATOMIC_RELAXED, __HIP_MEMORY_SCOPE_AGENT) < tgt) {}
    }
    __syncthreads();
}

__global__ void zero_kernel(float* __restrict__ p, int n) {
    int i = blockIdx.x * 256 + threadIdx.x;
    if (i < n) p[i] = 0.0f;
}

// W (= [Wx;Wh], 1280 x 4096) -> per-block LDS image:
// [jb(256)][ku(40)][plane(2)][lane(64)][j(8)]  (80 KB per jb, contiguous)
__global__ void packWz_kernel(const float* __restrict__ Wx, const float* __restrict__ Wh,
                              unsigned short* __restrict__ Wzf) {
    int e = blockIdx.x * 256 + threadIdx.x;
    if (e >= 1280 * 4096) return;
    int k = e >> 12, col = e & 4095;
    float w = (k < NDIN) ? Wx[(size_t)k * NG + col] : Wh[(size_t)(k - NDIN) * NG + col];
    float back;
    unsigned short w0 = bf_hi(w, &back);
    unsigned short w1 = bf_hi(w - back, &back);
    int g = col >> 10, j = col & 1023;
    int jb = j >> 2, jc = j & 3, n = g * 4 + jc;
    int ku = k >> 5, kr = k & 31;
    int lane = (kr >> 3) * 16 + n, j8 = kr & 7;
    size_t off = ((size_t)jb * 40 + ku) * 1024 + lane * 8 + j8;
    Wzf[off] = w0;          // plane 0 (hi)
    Wzf[off + 512] = w1;    // plane 1 (lo)
}

// x ([64][512][256]) -> A-frag order [t][ku(8)][mb(4)][lane(64)][j(8)], hi/lo
__global__ void packX_kernel(const float* __restrict__ x,
                             unsigned short* __restrict__ xf0, unsigned short* __restrict__ xf1) {
    int e = blockIdx.x * 256 + threadIdx.x;
    if (e >= NB * NT * NDIN) return;
    int k = e & 255, t = (e >> 8) & 511, m = e >> 17;
    float v = x[e];
    float back;
    unsigned short a0 = bf_hi(v, &back);
    unsigned short a1 = bf_hi(v - back, &back);
    int ku = k >> 5, kr = k & 31, mb = m >> 4;
    int lane = (kr >> 3) * 16 + (m & 15), j = kr & 7;
    size_t off = ((((size_t)t * 8 + ku) * 4 + mb) * 64 + lane) * 8 + j;
    xf0[off] = a0; xf1[off] = a1;
}

// Wo (1024 x 256) -> B-frag order [nb(16)][ku(32)][lane(64)][j(8)], hi/lo
__global__ void packWo_kernel(const float* __restrict__ Wo,
                              unsigned short* __restrict__ Wo0f, unsigned short* __restrict__ Wo1f) {
    int e = blockIdx.x * 256 + threadIdx.x;
    if (e >= NH * NDOUT) return;
    int k = e >> 8, n = e & 255;
    float w = Wo[e];
    float back;
    unsigned short w0 = bf_hi(w, &back);
    unsigned short w1 = bf_hi(w - back, &back);
    int nb = n >> 4, nl = n & 15, ku = k >> 5, kr = k & 31;
    int lane = (kr >> 3) * 16 + nl, j = kr & 7;
    size_t off = (((size_t)nb * 32 + ku) * 64 + lane) * 8 + j;
    Wo0f[off] = w0; Wo1f[off] = w1;
}

// ================= 256-block persistent kernel =================
// ALL 256 CUs run the z-GEMM: block jb owns h-cols [jb*4, jb*4+4) x 4 gates
// (M=64, N=16, K=1280). The 80KB W slice lives in LDS, loaded ONCE (zero W
// traffic in the loop). Per-step per-CU stream = A only (~320KB). Cell state c
// is thread-register-resident (each (row,col) owned by one thread forever).
// Blocks 0..127 additionally compute one proj K-half tile; 128..135 outred.
__global__ __launch_bounds__(512, 2) void persist_z256_kernel(
    const unsigned short* __restrict__ Wzf,
    const unsigned short* __restrict__ xf0, const unsigned short* __restrict__ xf1,
    const unsigned short* __restrict__ Wo0f, const unsigned short* __restrict__ Wo1f,
    unsigned short* __restrict__ hh, float* __restrict__ opart,
    const float* __restrict__ bias, const float* __restrict__ bo,
    float* __restrict__ out, unsigned* __restrict__ bar)
{
    extern __shared__ char dynlds[];
    unsigned short* wlds = (unsigned short*)dynlds;          // [40][2][64][8] = 80 KB
    float* red  = (float*)(dynlds + 81920);                  // 32 KB scratch (z: [8][1024], proj: [8][256])
    float* zfin = (float*)(dynlds + 114688);                 // [1024]

    const int bid = blockIdx.x, tid = threadIdx.x;
    const int lane = tid & 63, w = tid >> 6;

    // ---- one-time: W slice -> LDS (80 KB straight copy) ----
    {
        const unsigned short* src = Wzf + (size_t)bid * 40960;
        for (int i = tid; i < 5120; i += 512)
            *(short8*)(wlds + i * 8) = *(const short8*)(src + i * 8);
    }
    __syncthreads();

    // ---- per-thread gate-math constants (threads 0..255 own (row, col)) ----
    const int grow = tid >> 2, gjc = tid & 3;
    const int gj = bid * 4 + gjc;                            // global h-col
    const float b_i = bias[gj], b_f = bias[NH + gj], b_g = bias[2 * NH + gj], b_o = bias[3 * NH + gj];
    const int zb = ((grow >> 4) * 64 + (((grow & 15) >> 2) * 16) + gjc) * 4 + (grow & 3);
    const int kuh = gj >> 5, krh = gj & 31;
    const size_t hoff = ((size_t)(kuh * 4 + (grow >> 4))) * 512
                      + ((krh >> 3) * 16 + (grow & 15)) * 8 + (krh & 7);
    float creg = 0.0f;                                       // cell state, register-resident

    for (int t = 0; t <= NT + 1; ++t) {
        if (t < NT) {
            // ---- z-GEMM: M=64, N=16 (4 gates x 4 cols), K=1280, 3 planes ----
            float4v acc[4];
            #pragma unroll
            for (int mb = 0; mb < 4; ++mb) acc[mb] = (float4v){0.f, 0.f, 0.f, 0.f};

            const unsigned short* hbase = hh + (size_t)t * HSTEP;
            const int ku0 = w * 5;                           // wave-private K slice
            #pragma unroll
            for (int i = 0; i < 5; ++i) {
                const int ku = ku0 + i;
                const unsigned short *p0, *p1;
                if (ku < 8) {
                    p0 = xf0 + ((size_t)t * 8 + ku) * 2048;
                    p1 = xf1 + ((size_t)t * 8 + ku) * 2048;
                } else {
                    p0 = hbase + (size_t)(ku - 8) * 2048;
                    p1 = hbase + 65536 + (size_t)(ku - 8) * 2048;
                }
                short8 A0[4], A1[4];
                #pragma unroll
                for (int mb = 0; mb < 4; ++mb) {
                    A0[mb] = *(const short8*)(p0 + mb * 512 + lane * 8);
                    A1[mb] = *(const short8*)(p1 + mb * 512 + lane * 8);
                }
                short8 Wh = *(const short8*)(wlds + ku * 1024 + lane * 8);
                short8 Wl = *(const short8*)(wlds + ku * 1024 + 512 + lane * 8);
                #pragma unroll
                for (int mb = 0; mb < 4; ++mb) {
                    acc[mb] = __builtin_amdgcn_mfma_f32_16x16x32_bf16(A0[mb], Wh, acc[mb], 0, 0, 0);
                    acc[mb] = __builtin_amdgcn_mfma_f32_16x16x32_bf16(A0[mb], Wl, acc[mb], 0, 0, 0);
                    acc[mb] = __builtin_amdgcn_mfma_f32_16x16x32_bf16(A1[mb], Wh, acc[mb], 0, 0, 0);
                }
            }

            // cross-wave splitK reduce via LDS (8 waves x 4KB)
            {
                float* slab = red + w * 1024;
                #pragma unroll
                for (int mb = 0; mb < 4; ++mb)
                    *(float4v*)&slab[(mb * 64 + lane) * 4] = acc[mb];
            }
            __syncthreads();
            if (tid < 256) {
                float4v sum = (float4v){0.f, 0.f, 0.f, 0.f};
                #pragma unroll
                for (int ww = 0; ww < 8; ++ww)
                    sum = sum + *(const float4v*)&red[ww * 1024 + tid * 4];
                *(float4v*)&zfin[tid * 4] = sum;
            }
            __syncthreads();

            // gate math + register cell update + h write to fresh slab t+1
            if (tid < 256) {
                float zi = zfin[zb]      + b_i;
                float zf = zfin[zb + 16] + b_f;
                float zg = zfin[zb + 32] + b_g;
                float zo = zfin[zb + 48] + b_o;
                float iv = sigf(zi), fv = sigf(zf), gv = tanhf(zg), ov = sigf(zo);
                creg = fv * creg + iv * gv;
                float hv = ov * tanhf(creg);
                float back;
                unsigned short h0 = bf_hi(hv, &back);
                unsigned short h1 = bf_hi(hv - back, &back);
                unsigned short* hw = hh + (size_t)(t + 1) * HSTEP;
                sc_store_short(hw + hoff, h0);
                sc_store_short(hw + hoff + 65536, h1);       // lo plane
            }
        }

        if (bid < 128) {
            // ---- proj: one 16x16 tile x K-half of h(t-1) @ Wo -> opart ----
            if (t >= 1 && t <= NT) {
                const int tt = bid >> 1, kh = bid & 1;
                const int mbp = tt >> 4, nbp = tt & 15;
                const unsigned short* hb = hh + (size_t)t * HSTEP;
                float4v pacc = (float4v){0.f, 0.f, 0.f, 0.f};
                #pragma unroll
                for (int q = 0; q < 2; ++q) {
                    const int kup = kh * 16 + w * 2 + q;
                    const unsigned short* ap = hb + (size_t)(kup * 4 + mbp) * 512 + lane * 8;
                    short8 Ahi = *(const short8*)ap;
                    short8 Alo = *(const short8*)(ap + 65536);
                    const size_t wo = (((size_t)nbp * 32 + kup) * 64 + lane) * 8;
                    short8 Whi = *(const short8*)(Wo0f + wo);
                    short8 Wlo = *(const short8*)(Wo1f + wo);
                    pacc = __builtin_amdgcn_mfma_f32_16x16x32_bf16(Ahi, Whi, pacc, 0, 0, 0);
                    pacc = __builtin_amdgcn_mfma_f32_16x16x32_bf16(Ahi, Wlo, pacc, 0, 0, 0);
                    pacc = __builtin_amdgcn_mfma_f32_16x16x32_bf16(Alo, Whi, pacc, 0, 0, 0);
                }
                *(float4v*)&red[(w * 64 + lane) * 4] = pacc;
                __syncthreads();
                if (tid < 256) {
                    float s = 0.f;
                    #pragma unroll
                    for (int ww = 0; ww < 8; ++ww) s += red[ww * 256 + tid];
                    const int l = tid >> 2, r = tid & 3;
                    const int prow = mbp * 16 + (l >> 4) * 4 + r;
                    const int pcol = nbp * 16 + (l & 15);
                    sc_store_dword(opart + (size_t)(t & 1) * 32768
                                   + (size_t)(kh * 64 + prow) * NDOUT + pcol, s);
                }
            }
        } else if (bid < 136) {
            // ---- out-reduce of opart[(t-1)&1] -> out row t-2 ----
            if (t >= 2) {
                const int ob = bid - 128;
                const float* op = opart + (size_t)((t - 1) & 1) * 32768;
                int idx = ob * 512 + tid;                    // [0,4096)
                int m = idx >> 6, oc4 = (idx & 63) * 4;
                float4v s0, s1;
                LD2(s0, s1, &op[(size_t)m * NDOUT + oc4], &op[(size_t)(64 + m) * NDOUT + oc4]);
                float4v bv = *(const float4v*)&bo[oc4];
                float4v v = s0 + s1 + bv;
                float4v rr;
                rr[0] = fmaxf(v[0], 0.f); rr[1] = fmaxf(v[1], 0.f);
                rr[2] = fmaxf(v[2], 0.f); rr[3] = fmaxf(v[3], 0.f);
                *(float4v*)&out[((size_t)m * NT + (t - 2)) * NDOUT + oc4] = rr;
            }
        }

        gbar(bar, (unsigned)(t + 1) * GRIDN);
    }
}

extern "C" void kernel_launch(void* const* d_in, const int* in_sizes, int n_in,
                              void* d_out, int out_size, void* d_ws, size_t ws_size,
                              hipStream_t stream) {
    const float* x  = (const float*)d_in[0];
    const float* Wx = (const float*)d_in[1];
    const float* Wh = (const float*)d_in[2];
    const float* b  = (const float*)d_in[3];
    const float* Wo = (const float*)d_in[4];
    const float* bo = (const float*)d_in[5];
    float* out = (float*)d_out;
    char* ws = (char*)d_ws;

    const size_t hh_bytes = (size_t)(NT + 1) * HSTEP * 2;    // 513 x 256 KB

    size_t off = 0;
    unsigned* bar = (unsigned*)(ws + off);             off += 256;
    unsigned short* hh = (unsigned short*)(ws + off);  off += hh_bytes;
    size_t zero_floats = (256 + (size_t)HSTEP * 2) / 4;       // bar + hh slab0
    float* opart = (float*)(ws + off);                 off += (size_t)2 * 2 * NB * NDOUT * 4;
    unsigned short* Wzf = (unsigned short*)(ws + off); off += (size_t)1280 * 4096 * 2 * 2;  // 21 MB
    unsigned short* Wo0f = (unsigned short*)(ws + off); off += (size_t)NH * NDOUT * 2;
    unsigned short* Wo1f = (unsigned short*)(ws + off); off += (size_t)NH * NDOUT * 2;
    unsigned short* xf0 = (unsigned short*)(ws + off); off += (size_t)NB * NT * NDIN * 2;
    unsigned short* xf1 = (unsigned short*)(ws + off); off += (size_t)NB * NT * NDIN * 2;

    zero_kernel<<<(int)((zero_floats + 255) / 256), 256, 0, stream>>>((float*)ws, (int)zero_floats);
    packWz_kernel<<<(1280 * 4096 + 255) / 256, 256, 0, stream>>>(Wx, Wh, Wzf);
    packX_kernel<<<(NB * NT * NDIN + 255) / 256, 256, 0, stream>>>(x, xf0, xf1);
    packWo_kernel<<<(NH * NDOUT + 255) / 256, 256, 0, stream>>>(Wo, Wo0f, Wo1f);

    void* args[] = {(void*)&Wzf, (void*)&xf0, (void*)&xf1, (void*)&Wo0f, (void*)&Wo1f,
                    (void*)&hh, (void*)&opart, (void*)&b, (void*)&bo, (void*)&out, (void*)&bar};
    hipLaunchCooperativeKernel((void*)persist_z256_kernel, dim3(GRIDN), dim3(512),
                               args, (unsigned)LDSB, stream);
}

// Round 6
// 6016.272 us; speedup vs baseline: 1.4282x; 1.2351x over previous
//
#include <hip/hip_runtime.h>
#include <hip/hip_bf16.h>
#include <math.h>

#define NB 64
#define NT 512
#define NDIN 256
#define NH 1024
#define NG 4096
#define NDOUT 256

// 256 blocks: ALL do z (4 h-cols each); [0,128) also proj; [128,136) also outred
#define GRIDN 256
#define LDSB 114688        // 80K Wz + 32K red
#define HSTEP 131072       // shorts per h time-slab: [v(2)][ku(32)][mb(4)][512]

typedef __attribute__((ext_vector_type(8))) short short8;
typedef __attribute__((ext_vector_type(4))) float float4v;

__device__ __forceinline__ float sigf(float v) { return 1.0f / (1.0f + expf(-v)); }

__device__ __forceinline__ unsigned short bf_hi(float v, float* back) {
    __hip_bfloat16 b = __float2bfloat16(v);
    *back = __bfloat162float(b);
    union { __hip_bfloat16 b; unsigned short u; } cv; cv.b = b;
    return cv.u;
}

// ---- device-coherent (LLC) helpers ----
#define LD2(o0,o1,p0,p1)                                                         \
  asm volatile("global_load_dwordx4 %0, %2, off sc0 sc1\n\t"                     \
               "global_load_dwordx4 %1, %3, off sc0 sc1\n\t"                     \
               "s_waitcnt vmcnt(0)"                                              \
               : "=&v"(o0),"=&v"(o1) : "v"(p0),"v"(p1) : "memory")

__device__ __forceinline__ void sc_store_short(unsigned short* p, unsigned short v) {
    asm volatile("global_store_short %0, %1, off sc0 sc1" :: "v"(p), "v"((unsigned)v) : "memory");
}
__device__ __forceinline__ void sc_store_dword(float* p, float v) {
    asm volatile("global_store_dword %0, %1, off sc0 sc1" :: "v"(p), "v"(v) : "memory");
}

// Two-level tree barrier (monotonic counters, no reset race).
// Level 1: 32 group counters (128B apart, 8 arrivals each -> ~8-way contention).
// Level 2: group-last bumps root (32 adds). Everyone read-polls root.
// Serial depth ~3 LLC RTTs instead of ~256 chained RMWs on one line.
__device__ __forceinline__ void gbar_tree(unsigned* bar, int bid, int t) {
    asm volatile("s_waitcnt vmcnt(0)" ::: "memory");   // drain own sc-stores
    __syncthreads();
    if (threadIdx.x == 0) {
        unsigned* gcnt = bar + ((unsigned)bid >> 3) * 32;   // 32 groups of 8
        unsigned* root = bar + 32 * 32;
        unsigned old = __hip_atomic_fetch_add(gcnt, 1u, __ATOMIC_RELAXED, __HIP_MEMORY_SCOPE_AGENT);
        if (old == (unsigned)t * 8u + 7u)                   // last of my group this epoch
            __hip_atomic_fetch_add(root, 1u, __ATOMIC_RELAXED, __HIP_MEMORY_SCOPE_AGENT);
        const unsigned tgt = (unsigned)(t + 1) * 32u;
        while (__hip_atomic_load(root, __ATOMIC_RELAXED, __HIP_MEMORY_SCOPE_AGENT) < tgt) {}
    }
    __syncthreads();
}

__global__ void zero_kernel(float* __restrict__ p, int n) {
    int i = blockIdx.x * 256 + threadIdx.x;
    if (i < n) p[i] = 0.0f;
}

// W (= [Wx;Wh], 1280 x 4096) -> per-block LDS image:
// [jb(256)][ku(40)][plane(2)][lane(64)][j(8)]  (80 KB per jb, contiguous)
__global__ void packWz_kernel(const float* __restrict__ Wx, const float* __restrict__ Wh,
                              unsigned short* __restrict__ Wzf) {
    int e = blockIdx.x * 256 + threadIdx.x;
    if (e >= 1280 * 4096) return;
    int k = e >> 12, col = e & 4095;
    float w = (k < NDIN) ? Wx[(size_t)k * NG + col] : Wh[(size_t)(k - NDIN) * NG + col];
    float back;
    unsigned short w0 = bf_hi(w, &back);
    unsigned short w1 = bf_hi(w - back, &back);
    int g = col >> 10, j = col & 1023;
    int jb = j >> 2, jc = j & 3, n = g * 4 + jc;
    int ku = k >> 5, kr = k & 31;
    int lane = (kr >> 3) * 16 + n, j8 = kr & 7;
    size_t off = ((size_t)jb * 40 + ku) * 1024 + lane * 8 + j8;
    Wzf[off] = w0;          // plane 0 (hi)
    Wzf[off + 512] = w1;    // plane 1 (lo)
}

// x ([64][512][256]) -> A-frag order [t][ku(8)][mb(4)][lane(64)][j(8)], hi/lo
__global__ void packX_kernel(const float* __restrict__ x,
                             unsigned short* __restrict__ xf0, unsigned short* __restrict__ xf1) {
    int e = blockIdx.x * 256 + threadIdx.x;
    if (e >= NB * NT * NDIN) return;
    int k = e & 255, t = (e >> 8) & 511, m = e >> 17;
    float v = x[e];
    float back;
    unsigned short a0 = bf_hi(v, &back);
    unsigned short a1 = bf_hi(v - back, &back);
    int ku = k >> 5, kr = k & 31, mb = m >> 4;
    int lane = (kr >> 3) * 16 + (m & 15), j = kr & 7;
    size_t off = ((((size_t)t * 8 + ku) * 4 + mb) * 64 + lane) * 8 + j;
    xf0[off] = a0; xf1[off] = a1;
}

// Wo (1024 x 256) -> B-frag order [nb(16)][ku(32)][lane(64)][j(8)], hi/lo
__global__ void packWo_kernel(const float* __restrict__ Wo,
                              unsigned short* __restrict__ Wo0f, unsigned short* __restrict__ Wo1f) {
    int e = blockIdx.x * 256 + threadIdx.x;
    if (e >= NH * NDOUT) return;
    int k = e >> 8, n = e & 255;
    float w = Wo[e];
    float back;
    unsigned short w0 = bf_hi(w, &back);
    unsigned short w1 = bf_hi(w - back, &back);
    int nb = n >> 4, nl = n & 15, ku = k >> 5, kr = k & 31;
    int lane = (kr >> 3) * 16 + nl, j = kr & 7;
    size_t off = (((size_t)nb * 32 + ku) * 64 + lane) * 8 + j;
    Wo0f[off] = w0; Wo1f[off] = w1;
}

// ================= 256-block persistent kernel (r5 structure) =================
// Changes vs r5: tree barrier; splitK reduce fused with gate math (zfin and one
// __syncthreads deleted -- gate threads sum the 8 wave slabs directly).
__global__ __launch_bounds__(512, 2) void persist_z256_kernel(
    const unsigned short* __restrict__ Wzf,
    const unsigned short* __restrict__ xf0, const unsigned short* __restrict__ xf1,
    const unsigned short* __restrict__ Wo0f, const unsigned short* __restrict__ Wo1f,
    unsigned short* __restrict__ hh, float* __restrict__ opart,
    const float* __restrict__ bias, const float* __restrict__ bo,
    float* __restrict__ out, unsigned* __restrict__ bar)
{
    extern __shared__ char dynlds[];
    unsigned short* wlds = (unsigned short*)dynlds;          // [40][2][64][8] = 80 KB
    float* red  = (float*)(dynlds + 81920);                  // 32 KB (z: [8][1024], proj: [8][256])

    const int bid = blockIdx.x, tid = threadIdx.x;
    const int lane = tid & 63, w = tid >> 6;

    // ---- one-time: W slice -> LDS (80 KB straight copy) ----
    {
        const unsigned short* src = Wzf + (size_t)bid * 40960;
        for (int i = tid; i < 5120; i += 512)
            *(short8*)(wlds + i * 8) = *(const short8*)(src + i * 8);
    }
    __syncthreads();

    // ---- per-thread gate-math constants (threads 0..255 own (row, col)) ----
    const int grow = tid >> 2, gjc = tid & 3;
    const int gj = bid * 4 + gjc;                            // global h-col
    const float b_i = bias[gj], b_f = bias[NH + gj], b_g = bias[2 * NH + gj], b_o = bias[3 * NH + gj];
    const int zb = ((grow >> 4) * 64 + (((grow & 15) >> 2) * 16) + gjc) * 4 + (grow & 3);
    const int kuh = gj >> 5, krh = gj & 31;
    const size_t hoff = ((size_t)(kuh * 4 + (grow >> 4))) * 512
                      + ((krh >> 3) * 16 + (grow & 15)) * 8 + (krh & 7);
    float creg = 0.0f;                                       // cell state, register-resident

    for (int t = 0; t <= NT + 1; ++t) {
        if (t < NT) {
            // ---- z-GEMM: M=64, N=16 (4 gates x 4 cols), K=1280, 3 planes ----
            float4v acc[4];
            #pragma unroll
            for (int mb = 0; mb < 4; ++mb) acc[mb] = (float4v){0.f, 0.f, 0.f, 0.f};

            const unsigned short* hbase = hh + (size_t)t * HSTEP;
            const int ku0 = w * 5;                           // wave-private K slice
            #pragma unroll
            for (int i = 0; i < 5; ++i) {
                const int ku = ku0 + i;
                const unsigned short *p0, *p1;
                if (ku < 8) {
                    p0 = xf0 + ((size_t)t * 8 + ku) * 2048;
                    p1 = xf1 + ((size_t)t * 8 + ku) * 2048;
                } else {
                    p0 = hbase + (size_t)(ku - 8) * 2048;
                    p1 = hbase + 65536 + (size_t)(ku - 8) * 2048;
                }
                short8 A0[4], A1[4];
                #pragma unroll
                for (int mb = 0; mb < 4; ++mb) {
                    A0[mb] = *(const short8*)(p0 + mb * 512 + lane * 8);
                    A1[mb] = *(const short8*)(p1 + mb * 512 + lane * 8);
                }
                short8 Wh = *(const short8*)(wlds + ku * 1024 + lane * 8);
                short8 Wl = *(const short8*)(wlds + ku * 1024 + 512 + lane * 8);
                #pragma unroll
                for (int mb = 0; mb < 4; ++mb) {
                    acc[mb] = __builtin_amdgcn_mfma_f32_16x16x32_bf16(A0[mb], Wh, acc[mb], 0, 0, 0);
                    acc[mb] = __builtin_amdgcn_mfma_f32_16x16x32_bf16(A0[mb], Wl, acc[mb], 0, 0, 0);
                    acc[mb] = __builtin_amdgcn_mfma_f32_16x16x32_bf16(A1[mb], Wh, acc[mb], 0, 0, 0);
                }
            }

            // splitK slabs to LDS, one sync, then fused reduce+gate math
            {
                float* slab = red + w * 1024;
                #pragma unroll
                for (int mb = 0; mb < 4; ++mb)
                    *(float4v*)&slab[(mb * 64 + lane) * 4] = acc[mb];
            }
            __syncthreads();

            if (tid < 256) {
                float zi = b_i, zf = b_f, zg = b_g, zo = b_o;
                #pragma unroll
                for (int ww = 0; ww < 8; ++ww) {
                    const float* s = red + ww * 1024;
                    zi += s[zb]; zf += s[zb + 16]; zg += s[zb + 32]; zo += s[zb + 48];
                }
                float iv = sigf(zi), fv = sigf(zf), gv = tanhf(zg), ov = sigf(zo);
                creg = fv * creg + iv * gv;
                float hv = ov * tanhf(creg);
                float back;
                unsigned short h0 = bf_hi(hv, &back);
                unsigned short h1 = bf_hi(hv - back, &back);
                unsigned short* hw = hh + (size_t)(t + 1) * HSTEP;
                sc_store_short(hw + hoff, h0);
                sc_store_short(hw + hoff + 65536, h1);       // lo plane
            }
        }

        if (bid < 128) {
            // ---- proj: one 16x16 tile x K-half of h(t-1) @ Wo -> opart ----
            if (t >= 1 && t <= NT) {
                const int tt = bid >> 1, kh = bid & 1;
                const int mbp = tt >> 4, nbp = tt & 15;
                const unsigned short* hb = hh + (size_t)t * HSTEP;
                float4v pacc = (float4v){0.f, 0.f, 0.f, 0.f};
                #pragma unroll
                for (int q = 0; q < 2; ++q) {
                    const int kup = kh * 16 + w * 2 + q;
                    const unsigned short* ap = hb + (size_t)(kup * 4 + mbp) * 512 + lane * 8;
                    short8 Ahi = *(const short8*)ap;
                    short8 Alo = *(const short8*)(ap + 65536);
                    const size_t wo = (((size_t)nbp * 32 + kup) * 64 + lane) * 8;
                    short8 Whi = *(const short8*)(Wo0f + wo);
                    short8 Wlo = *(const short8*)(Wo1f + wo);
                    pacc = __builtin_amdgcn_mfma_f32_16x16x32_bf16(Ahi, Whi, pacc, 0, 0, 0);
                    pacc = __builtin_amdgcn_mfma_f32_16x16x32_bf16(Ahi, Wlo, pacc, 0, 0, 0);
                    pacc = __builtin_amdgcn_mfma_f32_16x16x32_bf16(Alo, Whi, pacc, 0, 0, 0);
                }
                __syncthreads();               // gate-reads of red must finish first
                *(float4v*)&red[(w * 64 + lane) * 4] = pacc;
                __syncthreads();
                if (tid < 256) {
                    float s = 0.f;
                    #pragma unroll
                    for (int ww = 0; ww < 8; ++ww) s += red[ww * 256 + tid];
                    const int l = tid >> 2, r = tid & 3;
                    const int prow = mbp * 16 + (l >> 4) * 4 + r;
                    const int pcol = nbp * 16 + (l & 15);
                    sc_store_dword(opart + (size_t)(t & 1) * 32768
                                   + (size_t)(kh * 64 + prow) * NDOUT + pcol, s);
                }
            }
        } else if (bid < 136) {
            // ---- out-reduce of opart[(t-1)&1] -> out row t-2 ----
            if (t >= 2) {
                const int ob = bid - 128;
                const float* op = opart + (size_t)((t - 1) & 1) * 32768;
                int idx = ob * 512 + tid;                    // [0,4096)
                int m = idx >> 6, oc4 = (idx & 63) * 4;
                float4v s0, s1;
                LD2(s0, s1, &op[(size_t)m * NDOUT + oc4], &op[(size_t)(64 + m) * NDOUT + oc4]);
                float4v bv = *(const float4v*)&bo[oc4];
                float4v v = s0 + s1 + bv;
                float4v rr;
                rr[0] = fmaxf(v[0], 0.f); rr[1] = fmaxf(v[1], 0.f);
                rr[2] = fmaxf(v[2], 0.f); rr[3] = fmaxf(v[3], 0.f);
                *(float4v*)&out[((size_t)m * NT + (t - 2)) * NDOUT + oc4] = rr;
            }
        }

        gbar_tree(bar, bid, t);
    }
}

extern "C" void kernel_launch(void* const* d_in, const int* in_sizes, int n_in,
                              void* d_out, int out_size, void* d_ws, size_t ws_size,
                              hipStream_t stream) {
    const float* x  = (const float*)d_in[0];
    const float* Wx = (const float*)d_in[1];
    const float* Wh = (const float*)d_in[2];
    const float* b  = (const float*)d_in[3];
    const float* Wo = (const float*)d_in[4];
    const float* bo = (const float*)d_in[5];
    float* out = (float*)d_out;
    char* ws = (char*)d_ws;

    const size_t hh_bytes = (size_t)(NT + 1) * HSTEP * 2;    // 513 x 256 KB

    size_t off = 0;
    unsigned* bar = (unsigned*)(ws + off);             off += 8192;   // 32 group lines + root
    unsigned short* hh = (unsigned short*)(ws + off);  off += hh_bytes;
    size_t zero_floats = (8192 + (size_t)HSTEP * 2) / 4;      // bar + hh slab0
    float* opart = (float*)(ws + off);                 off += (size_t)2 * 2 * NB * NDOUT * 4;
    unsigned short* Wzf = (unsigned short*)(ws + off); off += (size_t)1280 * 4096 * 2 * 2;  // 21 MB
    unsigned short* Wo0f = (unsigned short*)(ws + off); off += (size_t)NH * NDOUT * 2;
    unsigned short* Wo1f = (unsigned short*)(ws + off); off += (size_t)NH * NDOUT * 2;
    unsigned short* xf0 = (unsigned short*)(ws + off); off += (size_t)NB * NT * NDIN * 2;
    unsigned short* xf1 = (unsigned short*)(ws + off); off += (size_t)NB * NT * NDIN * 2;

    zero_kernel<<<(int)((zero_floats + 255) / 256), 256, 0, stream>>>((float*)ws, (int)zero_floats);
    packWz_kernel<<<(1280 * 4096 + 255) / 256, 256, 0, stream>>>(Wx, Wh, Wzf);
    packX_kernel<<<(NB * NT * NDIN + 255) / 256, 256, 0, stream>>>(x, xf0, xf1);
    packWo_kernel<<<(NH * NDOUT + 255) / 256, 256, 0, stream>>>(Wo, Wo0f, Wo1f);

    void* args[] = {(void*)&Wzf, (void*)&xf0, (void*)&xf1, (void*)&Wo0f, (void*)&Wo1f,
                    (void*)&hh, (void*)&opart, (void*)&b, (void*)&bo, (void*)&out, (void*)&bar};
    hipLaunchCooperativeKernel((void*)persist_z256_kernel, dim3(GRIDN), dim3(512),
                               args, (unsigned)LDSB, stream);
}

// Round 7
// 5614.911 us; speedup vs baseline: 1.5302x; 1.0715x over previous
//
#include <hip/hip_runtime.h>
#include <hip/hip_bf16.h>
#include <math.h>

#define NB 64
#define NT 512
#define NDIN 256
#define NH 1024
#define NG 4096
#define NDOUT 256

// 256 blocks: ALL do z (4 h-cols each) AND proj (1 tile x K-quarter);
// blocks [0,8) also outred.
#define GRIDN 256
#define LDSB 122880        // 80K Wz + 32K red(z) + 8K red2(proj)
#define HSTEP 131072       // shorts per h time-slab: [v(2)][ku(32)][mb(4)][512]

typedef __attribute__((ext_vector_type(8))) short short8;
typedef __attribute__((ext_vector_type(4))) float float4v;

__device__ __forceinline__ float sigf(float v) { return 1.0f / (1.0f + expf(-v)); }

__device__ __forceinline__ unsigned short bf_hi(float v, float* back) {
    __hip_bfloat16 b = __float2bfloat16(v);
    *back = __bfloat162float(b);
    union { __hip_bfloat16 b; unsigned short u; } cv; cv.b = b;
    return cv.u;
}

// ---- device-coherent (LLC) helpers ----
#define LD4(o0,o1,o2,o3,p0,p1,p2,p3)                                             \
  asm volatile("global_load_dwordx4 %0, %4, off sc0 sc1\n\t"                     \
               "global_load_dwordx4 %1, %5, off sc0 sc1\n\t"                     \
               "global_load_dwordx4 %2, %6, off sc0 sc1\n\t"                     \
               "global_load_dwordx4 %3, %7, off sc0 sc1\n\t"                     \
               "s_waitcnt vmcnt(0)"                                              \
               : "=&v"(o0),"=&v"(o1),"=&v"(o2),"=&v"(o3)                         \
               : "v"(p0),"v"(p1),"v"(p2),"v"(p3) : "memory")

__device__ __forceinline__ void sc_store_short(unsigned short* p, unsigned short v) {
    asm volatile("global_store_short %0, %1, off sc0 sc1" :: "v"(p), "v"((unsigned)v) : "memory");
}
__device__ __forceinline__ void sc_store_dword(float* p, float v) {
    asm volatile("global_store_dword %0, %1, off sc0 sc1" :: "v"(p), "v"(v) : "memory");
}

// Two-level tree barrier (validated r6). Monotonic counters, no reset race.
__device__ __forceinline__ void gbar_tree(unsigned* bar, int bid, int t) {
    asm volatile("s_waitcnt vmcnt(0)" ::: "memory");   // drain own sc-stores
    __syncthreads();
    if (threadIdx.x == 0) {
        unsigned* gcnt = bar + ((unsigned)bid >> 3) * 32;   // 32 groups of 8
        unsigned* root = bar + 32 * 32;
        unsigned old = __hip_atomic_fetch_add(gcnt, 1u, __ATOMIC_RELAXED, __HIP_MEMORY_SCOPE_AGENT);
        if (old == (unsigned)t * 8u + 7u)                   // last of my group this epoch
            __hip_atomic_fetch_add(root, 1u, __ATOMIC_RELAXED, __HIP_MEMORY_SCOPE_AGENT);
        const unsigned tgt = (unsigned)(t + 1) * 32u;
        while (__hip_atomic_load(root, __ATOMIC_RELAXED, __HIP_MEMORY_SCOPE_AGENT) < tgt) {}
    }
    __syncthreads();
}

__global__ void zero_kernel(float* __restrict__ p, int n) {
    int i = blockIdx.x * 256 + threadIdx.x;
    if (i < n) p[i] = 0.0f;
}

// W (= [Wx;Wh], 1280 x 4096) -> per-block LDS image:
// [jb(256)][ku(40)][plane(2)][lane(64)][j(8)]  (80 KB per jb, contiguous)
__global__ void packWz_kernel(const float* __restrict__ Wx, const float* __restrict__ Wh,
                              unsigned short* __restrict__ Wzf) {
    int e = blockIdx.x * 256 + threadIdx.x;
    if (e >= 1280 * 4096) return;
    int k = e >> 12, col = e & 4095;
    float w = (k < NDIN) ? Wx[(size_t)k * NG + col] : Wh[(size_t)(k - NDIN) * NG + col];
    float back;
    unsigned short w0 = bf_hi(w, &back);
    unsigned short w1 = bf_hi(w - back, &back);
    int g = col >> 10, j = col & 1023;
    int jb = j >> 2, jc = j & 3, n = g * 4 + jc;
    int ku = k >> 5, kr = k & 31;
    int lane = (kr >> 3) * 16 + n, j8 = kr & 7;
    size_t off = ((size_t)jb * 40 + ku) * 1024 + lane * 8 + j8;
    Wzf[off] = w0;          // plane 0 (hi)
    Wzf[off + 512] = w1;    // plane 1 (lo)
}

// x ([64][512][256]) -> A-frag order [t][ku(8)][mb(4)][lane(64)][j(8)], hi/lo
__global__ void packX_kernel(const float* __restrict__ x,
                             unsigned short* __restrict__ xf0, unsigned short* __restrict__ xf1) {
    int e = blockIdx.x * 256 + threadIdx.x;
    if (e >= NB * NT * NDIN) return;
    int k = e & 255, t = (e >> 8) & 511, m = e >> 17;
    float v = x[e];
    float back;
    unsigned short a0 = bf_hi(v, &back);
    unsigned short a1 = bf_hi(v - back, &back);
    int ku = k >> 5, kr = k & 31, mb = m >> 4;
    int lane = (kr >> 3) * 16 + (m & 15), j = kr & 7;
    size_t off = ((((size_t)t * 8 + ku) * 4 + mb) * 64 + lane) * 8 + j;
    xf0[off] = a0; xf1[off] = a1;
}

// Wo (1024 x 256) -> B-frag order [nb(16)][ku(32)][lane(64)][j(8)], hi/lo
__global__ void packWo_kernel(const float* __restrict__ Wo,
                              unsigned short* __restrict__ Wo0f, unsigned short* __restrict__ Wo1f) {
    int e = blockIdx.x * 256 + threadIdx.x;
    if (e >= NH * NDOUT) return;
    int k = e >> 8, n = e & 255;
    float w = Wo[e];
    float back;
    unsigned short w0 = bf_hi(w, &back);
    unsigned short w1 = bf_hi(w - back, &back);
    int nb = n >> 4, nl = n & 15, ku = k >> 5, kr = k & 31;
    int lane = (kr >> 3) * 16 + nl, j = kr & 7;
    size_t off = (((size_t)nb * 32 + ku) * 64 + lane) * 8 + j;
    Wo0f[off] = w0; Wo1f[off] = w1;
}

// z h-load set (one ku = w*4+kk of the h slab): 8 x 16B loads
#define ZLOAD(S0, S1, kk) do {                                                    \
    const unsigned short* _p = hb0 + (size_t)(w4 + (kk)) * 2048 + lane8;          \
    S0[0] = *(const short8*)(_p);        S0[1] = *(const short8*)(_p + 512);      \
    S0[2] = *(const short8*)(_p + 1024); S0[3] = *(const short8*)(_p + 1536);     \
    const unsigned short* _q = _p + 65536;                                        \
    S1[0] = *(const short8*)(_q);        S1[1] = *(const short8*)(_q + 512);      \
    S1[2] = *(const short8*)(_q + 1024); S1[3] = *(const short8*)(_q + 1536);     \
} while (0)

// z MFMA set for one h-ku (3 planes x 4 mb)
#define ZMFMA(S0, S1, kk) do {                                                    \
    const unsigned short* _wp = wlds + (8 + w4 + (kk)) * 1024 + lane8;            \
    short8 _Wh = *(const short8*)(_wp);                                           \
    short8 _Wl = *(const short8*)(_wp + 512);                                     \
    acc[0] = __builtin_amdgcn_mfma_f32_16x16x32_bf16(S0[0], _Wh, acc[0], 0, 0, 0);\
    acc[0] = __builtin_amdgcn_mfma_f32_16x16x32_bf16(S0[0], _Wl, acc[0], 0, 0, 0);\
    acc[0] = __builtin_amdgcn_mfma_f32_16x16x32_bf16(S1[0], _Wh, acc[0], 0, 0, 0);\
    acc[1] = __builtin_amdgcn_mfma_f32_16x16x32_bf16(S0[1], _Wh, acc[1], 0, 0, 0);\
    acc[1] = __builtin_amdgcn_mfma_f32_16x16x32_bf16(S0[1], _Wl, acc[1], 0, 0, 0);\
    acc[1] = __builtin_amdgcn_mfma_f32_16x16x32_bf16(S1[1], _Wh, acc[1], 0, 0, 0);\
    acc[2] = __builtin_amdgcn_mfma_f32_16x16x32_bf16(S0[2], _Wh, acc[2], 0, 0, 0);\
    acc[2] = __builtin_amdgcn_mfma_f32_16x16x32_bf16(S0[2], _Wl, acc[2], 0, 0, 0);\
    acc[2] = __builtin_amdgcn_mfma_f32_16x16x32_bf16(S1[2], _Wh, acc[2], 0, 0, 0);\
    acc[3] = __builtin_amdgcn_mfma_f32_16x16x32_bf16(S0[3], _Wh, acc[3], 0, 0, 0);\
    acc[3] = __builtin_amdgcn_mfma_f32_16x16x32_bf16(S0[3], _Wl, acc[3], 0, 0, 0);\
    acc[3] = __builtin_amdgcn_mfma_f32_16x16x32_bf16(S1[3], _Wh, acc[3], 0, 0, 0);\
} while (0)

// ================= 256-block persistent kernel (r6 + pipeline) =================
// vs r6: (1) per-wave K re-tile: 1 x-ku + 4 h-ku; the x-partials for step t+1
// are computed at the END of iteration t (before the barrier), overlapping
// the h-store drain + barrier wait; (2) h loads double-buffered 2-ku at a time;
// (3) proj spread over all 256 blocks (64 tiles x 4 K-quarters, 1 ku/wave),
// reduced by threads 256-511 in parallel with the gate threads.
__global__ __launch_bounds__(512, 2) void persist_z256_kernel(
    const unsigned short* __restrict__ Wzf,
    const unsigned short* __restrict__ xf0, const unsigned short* __restrict__ xf1,
    const unsigned short* __restrict__ Wo0f, const unsigned short* __restrict__ Wo1f,
    unsigned short* __restrict__ hh, float* __restrict__ opart,
    const float* __restrict__ bias, const float* __restrict__ bo,
    float* __restrict__ out, unsigned* __restrict__ bar)
{
    extern __shared__ char dynlds[];
    unsigned short* wlds = (unsigned short*)dynlds;          // [40][2][64][8] = 80 KB
    float* red  = (float*)(dynlds + 81920);                  // [8][1024] z splitK slabs
    float* red2 = (float*)(dynlds + 114688);                 // [8][256] proj slabs

    const int bid = blockIdx.x, tid = threadIdx.x;
    const int lane = tid & 63, w = tid >> 6;
    const int lane8 = lane * 8, w4 = w * 4;

    // ---- one-time: W slice -> LDS (80 KB straight copy) ----
    {
        const unsigned short* src = Wzf + (size_t)bid * 40960;
        for (int i = tid; i < 5120; i += 512)
            *(short8*)(wlds + i * 8) = *(const short8*)(src + i * 8);
    }
    __syncthreads();

    // ---- per-thread gate-math constants (threads 0..255 own (row, col)) ----
    const int grow = tid >> 2, gjc = tid & 3;
    const int gj = bid * 4 + gjc;                            // global h-col
    const float b_i = bias[gj], b_f = bias[NH + gj], b_g = bias[2 * NH + gj], b_o = bias[3 * NH + gj];
    const int zb = ((grow >> 4) * 64 + (((grow & 15) >> 2) * 16) + gjc) * 4 + (grow & 3);
    const int kuh = gj >> 5, krh = gj & 31;
    const size_t hoff = ((size_t)(kuh * 4 + (grow >> 4))) * 512
                      + ((krh >> 3) * 16 + (grow & 15)) * 8 + (krh & 7);
    float creg = 0.0f;                                       // cell state, register-resident

    // ---- proj constants: block owns tile (mbp,nbp) x K-quarter kq; wave owns 1 ku
    const int kq = bid & 3, tt0 = bid >> 2;
    const int mbp = tt0 >> 4, nbp = tt0 & 15;
    const int kup = kq * 8 + w;
    const size_t wo_off = (((size_t)nbp * 32 + kup) * 64 + lane) * 8;
    const short8 PWh = *(const short8*)(Wo0f + wo_off);      // Wo frags loop-invariant
    const short8 PWl = *(const short8*)(Wo1f + wo_off);

    // ---- x-part prologue for t=0: acc = x(0) partial (wave's x-ku = w) ----
    float4v acc[4];
    {
        const unsigned short* xp0 = xf0 + (size_t)w * 2048 + lane8;
        const unsigned short* xp1 = xf1 + (size_t)w * 2048 + lane8;
        short8 X0[4], X1[4];
        #pragma unroll
        for (int mb = 0; mb < 4; ++mb) {
            X0[mb] = *(const short8*)(xp0 + mb * 512);
            X1[mb] = *(const short8*)(xp1 + mb * 512);
        }
        const short8 Wh = *(const short8*)(wlds + w * 1024 + lane8);
        const short8 Wl = *(const short8*)(wlds + w * 1024 + 512 + lane8);
        #pragma unroll
        for (int mb = 0; mb < 4; ++mb) {
            float4v a = (float4v){0.f, 0.f, 0.f, 0.f};
            a = __builtin_amdgcn_mfma_f32_16x16x32_bf16(X0[mb], Wh, a, 0, 0, 0);
            a = __builtin_amdgcn_mfma_f32_16x16x32_bf16(X0[mb], Wl, a, 0, 0, 0);
            a = __builtin_amdgcn_mfma_f32_16x16x32_bf16(X1[mb], Wh, a, 0, 0, 0);
            acc[mb] = a;
        }
    }

    for (int t = 0; t <= NT + 1; ++t) {
        const int projA = (t >= 1 && t <= NT);
        const unsigned short* hb0 = hh + (size_t)t * HSTEP;  // h(t) slab, hi plane

        // proj loads issued first (deepest latency hiding)
        short8 PAh, PAl;
        if (projA) {
            const unsigned short* ap = hb0 + (size_t)(kup * 4 + mbp) * 512 + lane8;
            PAh = *(const short8*)ap;
            PAl = *(const short8*)(ap + 65536);
        }

        if (t < NT) {
            // ---- z h-part: K=1024 over 4 ku/wave, a/b double-buffered loads ----
            short8 A0a[4], A1a[4], A0b[4], A1b[4];
            ZLOAD(A0a, A1a, 0);
            ZLOAD(A0b, A1b, 1);
            ZMFMA(A0a, A1a, 0);
            ZLOAD(A0a, A1a, 2);
            ZMFMA(A0b, A1b, 1);
            ZLOAD(A0b, A1b, 3);
            ZMFMA(A0a, A1a, 2);
            ZMFMA(A0b, A1b, 3);

            // splitK slabs to LDS (consumes acc)
            float* slab = red + w * 1024;
            #pragma unroll
            for (int mb = 0; mb < 4; ++mb)
                *(float4v*)&slab[(mb * 64 + lane) * 4] = acc[mb];
        }

        if (projA) {
            float4v pacc = (float4v){0.f, 0.f, 0.f, 0.f};
            pacc = __builtin_amdgcn_mfma_f32_16x16x32_bf16(PAh, PWh, pacc, 0, 0, 0);
            pacc = __builtin_amdgcn_mfma_f32_16x16x32_bf16(PAh, PWl, pacc, 0, 0, 0);
            pacc = __builtin_amdgcn_mfma_f32_16x16x32_bf16(PAl, PWh, pacc, 0, 0, 0);
            *(float4v*)&red2[(w * 64 + lane) * 4] = pacc;
        }

        // x-part for step t+1 (no h dependency) -> overlaps reduce/stores/barrier
        if (t + 1 < NT) {
            const unsigned short* xp0 = xf0 + ((size_t)(t + 1) * 8 + w) * 2048 + lane8;
            const unsigned short* xp1 = xf1 + ((size_t)(t + 1) * 8 + w) * 2048 + lane8;
            short8 X0[4], X1[4];
            #pragma unroll
            for (int mb = 0; mb < 4; ++mb) {
                X0[mb] = *(const short8*)(xp0 + mb * 512);
                X1[mb] = *(const short8*)(xp1 + mb * 512);
            }
            const short8 Wh = *(const short8*)(wlds + w * 1024 + lane8);
            const short8 Wl = *(const short8*)(wlds + w * 1024 + 512 + lane8);
            #pragma unroll
            for (int mb = 0; mb < 4; ++mb) {
                float4v a = (float4v){0.f, 0.f, 0.f, 0.f};
                a = __builtin_amdgcn_mfma_f32_16x16x32_bf16(X0[mb], Wh, a, 0, 0, 0);
                a = __builtin_amdgcn_mfma_f32_16x16x32_bf16(X0[mb], Wl, a, 0, 0, 0);
                a = __builtin_amdgcn_mfma_f32_16x16x32_bf16(X1[mb], Wh, a, 0, 0, 0);
                acc[mb] = a;
            }
        }

        __syncthreads();

        if (t < NT && tid < 256) {
            // fused splitK reduce + gate math + h(t+1) store
            float zi = b_i, zf = b_f, zg = b_g, zo = b_o;
            #pragma unroll
            for (int ww = 0; ww < 8; ++ww) {
                const float* s = red + ww * 1024;
                zi += s[zb]; zf += s[zb + 16]; zg += s[zb + 32]; zo += s[zb + 48];
            }
            float iv = sigf(zi), fv = sigf(zf), gv = tanhf(zg), ov = sigf(zo);
            creg = fv * creg + iv * gv;
            float hv = ov * tanhf(creg);
            float back;
            unsigned short h0 = bf_hi(hv, &back);
            unsigned short h1 = bf_hi(hv - back, &back);
            unsigned short* hw = hh + (size_t)(t + 1) * HSTEP;
            sc_store_short(hw + hoff, h0);
            sc_store_short(hw + hoff + 65536, h1);           // lo plane
        }

        if (projA && tid >= 256) {
            // proj reduce (parallel with gate threads) -> opart[parity][kq]
            const int p = tid & 255;
            float s = 0.f;
            #pragma unroll
            for (int ww = 0; ww < 8; ++ww) s += red2[ww * 256 + p];
            const int l = p >> 2, r = p & 3;
            const int prow = mbp * 16 + (l >> 4) * 4 + r;
            const int pcol = nbp * 16 + (l & 15);
            sc_store_dword(opart + (size_t)(t & 1) * 65536 + (size_t)kq * 16384
                           + (size_t)prow * NDOUT + pcol, s);
        }

        if (bid < 8 && t >= 2) {
            // ---- out-reduce of opart[(t-1)&1] (4 K-quarters) -> out row t-2 ----
            const float* op = opart + (size_t)((t - 1) & 1) * 65536;
            int idx = bid * 512 + tid;                       // [0,4096)
            int m = idx >> 6, oc4 = (idx & 63) * 4;
            float4v s0, s1, s2, s3;
            LD4(s0, s1, s2, s3,
                &op[(size_t)m * NDOUT + oc4],
                &op[16384 + (size_t)m * NDOUT + oc4],
                &op[32768 + (size_t)m * NDOUT + oc4],
                &op[49152 + (size_t)m * NDOUT + oc4]);
            float4v bv = *(const float4v*)&bo[oc4];
            float4v v = s0 + s1 + s2 + s3 + bv;
            float4v rr;
            rr[0] = fmaxf(v[0], 0.f); rr[1] = fmaxf(v[1], 0.f);
            rr[2] = fmaxf(v[2], 0.f); rr[3] = fmaxf(v[3], 0.f);
            *(float4v*)&out[((size_t)m * NT + (t - 2)) * NDOUT + oc4] = rr;
        }

        gbar_tree(bar, bid, t);
    }
}

extern "C" void kernel_launch(void* const* d_in, const int* in_sizes, int n_in,
                              void* d_out, int out_size, void* d_ws, size_t ws_size,
                              hipStream_t stream) {
    const float* x  = (const float*)d_in[0];
    const float* Wx = (const float*)d_in[1];
    const float* Wh = (const float*)d_in[2];
    const float* b  = (const float*)d_in[3];
    const float* Wo = (const float*)d_in[4];
    const float* bo = (const float*)d_in[5];
    float* out = (float*)d_out;
    char* ws = (char*)d_ws;

    const size_t hh_bytes = (size_t)(NT + 1) * HSTEP * 2;    // 513 x 256 KB

    size_t off = 0;
    unsigned* bar = (unsigned*)(ws + off);             off += 8192;   // tree barrier lines
    unsigned short* hh = (unsigned short*)(ws + off);  off += hh_bytes;
    size_t zero_floats = (8192 + (size_t)HSTEP * 2) / 4;      // bar + hh slab0
    float* opart = (float*)(ws + off);                 off += (size_t)2 * 4 * NB * NDOUT * 4;  // 512 KB
    unsigned short* Wzf = (unsigned short*)(ws + off); off += (size_t)1280 * 4096 * 2 * 2;     // 21 MB
    unsigned short* Wo0f = (unsigned short*)(ws + off); off += (size_t)NH * NDOUT * 2;
    unsigned short* Wo1f = (unsigned short*)(ws + off); off += (size_t)NH * NDOUT * 2;
    unsigned short* xf0 = (unsigned short*)(ws + off); off += (size_t)NB * NT * NDIN * 2;
    unsigned short* xf1 = (unsigned short*)(ws + off); off += (size_t)NB * NT * NDIN * 2;

    zero_kernel<<<(int)((zero_floats + 255) / 256), 256, 0, stream>>>((float*)ws, (int)zero_floats);
    packWz_kernel<<<(1280 * 4096 + 255) / 256, 256, 0, stream>>>(Wx, Wh, Wzf);
    packX_kernel<<<(NB * NT * NDIN + 255) / 256, 256, 0, stream>>>(x, xf0, xf1);
    packWo_kernel<<<(NH * NDOUT + 255) / 256, 256, 0, stream>>>(Wo, Wo0f, Wo1f);

    void* args[] = {(void*)&Wzf, (void*)&xf0, (void*)&xf1, (void*)&Wo0f, (void*)&Wo1f,
                    (void*)&hh, (void*)&opart, (void*)&b, (void*)&bo, (void*)&out, (void*)&bar};
    hipLaunchCooperativeKernel((void*)persist_z256_kernel, dim3(GRIDN), dim3(512),
                               args, (unsigned)LDSB, stream);
}